// Round 1
// baseline (403.653 us; speedup 1.0000x reference)
//
#include <hip/hip_runtime.h>
#include <hip/hip_bf16.h>

#define E_NUM 8
#define I_DIM 2816
#define D_DIM 1024
#define T_NUM 1024
#define A_TOP 2
#define NPAIR (T_NUM * A_TOP)   // 2048
#define PADROWS 4096            // worst-case 256-padded rows: 2048 + 8*255 = 4088 -> 4096
#define MT1 (PADROWS / 256)     // 16 stage1 m-tiles
#define MT2 (PADROWS / 128)     // 32 stage2 m-tiles
#define KSPLIT 4
#define KCHUNK (I_DIM / KSPLIT) // 704
#define KT2 (KCHUNK / 32)       // 22

// ws layout: [0,64) meta, [64,+PADROWS*4) pairs, hbuf @16384, xbf after
#define HB_OFF    16384ULL
#define HB_BYTES  ((unsigned long long)PADROWS * I_DIM * 2ULL)
#define XBF_OFF   (HB_OFF + HB_BYTES)

// LDS XOR swizzle: row r, 16B-chunk c stored at chunk c ^ SW(r). Applied as
// pre-swizzled GLOBAL source for global_load_lds (A), swizzled LDS store (B),
// and the same XOR on every ds_read_b128. Breaks the 8-way bank conflict of
// row-major [rows][32]bf16 (64B row stride) down to ~2-way (free, m136).
#define SW(r) (((r) ^ ((r) >> 2)) & 3)

typedef __bf16 bf16x8 __attribute__((ext_vector_type(8)));
typedef float  f32x4  __attribute__((ext_vector_type(4)));

__device__ inline unsigned pk2(float a, float b) {
  __hip_bfloat162 h = __float22bfloat162_rn(make_float2(a, b));
  union { __hip_bfloat162 h; unsigned u; } c; c.h = h; return c.u;
}
__device__ inline uint4 pack8(float4 a, float4 b) {
  return make_uint4(pk2(a.x, a.y), pk2(a.z, a.w), pk2(b.x, b.y), pk2(b.z, b.w));
}
__device__ inline unsigned short f2bf(float f) {
  __hip_bfloat16 h = __float2bfloat16(f);
  union { __hip_bfloat16 h; unsigned short u; } c; c.h = h; return c.u;
}
__device__ inline void gload_lds16(const unsigned short* g, unsigned short* l) {
  __builtin_amdgcn_global_load_lds((const __attribute__((address_space(1))) void*)g,
                                   (__attribute__((address_space(3))) void*)l, 16, 0, 0);
}

// ---------------- kernel 1: bucket pairs by expert, 256-padded segments -------
__global__ __launch_bounds__(256) void sort_pairs_kernel(
    const int* __restrict__ eidx, int* __restrict__ meta, int* __restrict__ pairs)
{
  __shared__ int cnt[E_NUM];
  __shared__ int pstart[E_NUM + 1];
  __shared__ int cur[E_NUM];
  int tid = threadIdx.x;
  if (tid < E_NUM) cnt[tid] = 0;
  __syncthreads();
  for (int p = tid; p < NPAIR; p += 256) atomicAdd(&cnt[eidx[p] & 7], 1);
  for (int i = tid; i < PADROWS; i += 256) pairs[i] = -1;
  __syncthreads();
  if (tid == 0) {
    int s = 0;
    for (int e = 0; e < E_NUM; ++e) {
      pstart[e] = s; cur[e] = s;
      s += ((cnt[e] + 255) / 256) * 256;   // 256-pad: M-tile256 reads weights ~1.5x not 2.5x
    }
    pstart[E_NUM] = s;
  }
  __syncthreads();
  for (int p = tid; p < NPAIR; p += 256) {
    int e = eidx[p] & 7;
    int pos = atomicAdd(&cur[e], 1);
    pairs[pos] = p;
  }
  __syncthreads();
  if (tid <= E_NUM) meta[tid] = pstart[tid];
}

// ---------------- x: fp32 -> bf16 ----------------
__global__ __launch_bounds__(256) void convertx_kernel(
    const float* __restrict__ in, unsigned short* __restrict__ out)
{
  size_t i = (size_t)(blockIdx.x * 256 + threadIdx.x) * 8;
  const float4* p = (const float4*)(in + i);
  *(uint4*)(out + i) = pack8(p[0], p[1]);
}

// ---------------- stage1: h = silu(X w1^T) * (X w3^T) -------------------------
// grid (22, 16), block 512 = 8 waves (4Mx2N), tile 256x128, wave-tile 64x64
// (both matrices). BK=32 dbuf. LDS exactly 64 KB.
__global__ __launch_bounds__(512, 2) void stage1_v6(
    const unsigned short* __restrict__ xbf, const float* __restrict__ w1,
    const float* __restrict__ w3, const int* __restrict__ meta,
    const int* __restrict__ pairs, unsigned short* __restrict__ hbuf)
{
  int mtile = blockIdx.y;
  if (mtile * 256 >= meta[E_NUM]) return;
  if (pairs[mtile * 256] < 0) return;      // all-padding 256-tile
  int e = 0;
  while (meta[e + 1] <= mtile * 256) ++e;
  int ntile = blockIdx.x;   // 128 cols of I

  __shared__ alignas(16) unsigned short As[2][256 * 32];   // 2 x 16 KB
  __shared__ alignas(16) unsigned short B1s[2][128 * 32];  // 2 x 8 KB
  __shared__ alignas(16) unsigned short B3s[2][128 * 32];  // 2 x 8 KB

  int tid = threadIdx.x;
  int lane = tid & 63, w = tid >> 6;
  int wm = w >> 1, wn = w & 1, lrow = lane & 15, quad = lane >> 4;
  int rq = (quad ^ SW(lrow)) * 8;          // swizzled read chunk (elems); SW(row)==SW(lrow)

  // A staging: wave w, issue j: rows 32w+16j + lane/4, global chunk pre-swizzled
  int axoff[2];
#pragma unroll
  for (int j = 0; j < 2; ++j) {
    int r = 32 * w + 16 * j + (lane >> 2);
    int p = pairs[mtile * 256 + r];
    int tok = (p >= 0) ? (p >> 1) : 0;
    axoff[j] = tok * D_DIM + (((lane & 3) ^ SW(r)) * 8);
  }
  // B staging: thread t -> row t/4 (0..127), global chunk t%4, swizzled LDS slot
  int brow = tid >> 2;
  const float* pw1 = w1 + ((size_t)e * I_DIM + ntile * 128 + brow) * D_DIM + (tid & 3) * 8;
  const float* pw3 = w3 + ((size_t)e * I_DIM + ntile * 128 + brow) * D_DIM + (tid & 3) * 8;
  int bws = brow * 32 + (((tid & 3) ^ SW(brow)) * 8);

  f32x4 acc1[4][4], acc3[4][4];
#pragma unroll
  for (int i = 0; i < 4; ++i)
#pragma unroll
    for (int j = 0; j < 4; ++j) {
      acc1[i][j] = (f32x4){0.f, 0.f, 0.f, 0.f};
      acc3[i][j] = (f32x4){0.f, 0.f, 0.f, 0.f};
    }

  // prologue: K-tile 0
  float4 r1[2], r3[2];
  r1[0] = *(const float4*)(pw1);     r1[1] = *(const float4*)(pw1 + 4);
  r3[0] = *(const float4*)(pw3);     r3[1] = *(const float4*)(pw3 + 4);
  gload_lds16(xbf + axoff[0], &As[0][(32 * w) * 32]);
  gload_lds16(xbf + axoff[1], &As[0][(32 * w + 16) * 32]);
  *(uint4*)&B1s[0][bws] = pack8(r1[0], r1[1]);
  *(uint4*)&B3s[0][bws] = pack8(r3[0], r3[1]);

  const int KT = D_DIM / 32;   // 32
  for (int k = 0; k < KT; ++k) {
    __syncthreads();
    int kk = k & 1;
    if (k + 1 < KT) {
      int kn = (k + 1) * 32;
      r1[0] = *(const float4*)(pw1 + kn); r1[1] = *(const float4*)(pw1 + kn + 4);
      r3[0] = *(const float4*)(pw3 + kn); r3[1] = *(const float4*)(pw3 + kn + 4);
      gload_lds16(xbf + axoff[0] + kn, &As[kk ^ 1][(32 * w) * 32]);
      gload_lds16(xbf + axoff[1] + kn, &As[kk ^ 1][(32 * w + 16) * 32]);
    }
    bf16x8 af[4];
#pragma unroll
    for (int mi = 0; mi < 4; ++mi)
      af[mi] = *(const bf16x8*)&As[kk][(wm * 64 + mi * 16 + lrow) * 32 + rq];
#pragma unroll
    for (int ni = 0; ni < 4; ++ni) {
      bf16x8 b1 = *(const bf16x8*)&B1s[kk][(wn * 64 + ni * 16 + lrow) * 32 + rq];
#pragma unroll
      for (int mi = 0; mi < 4; ++mi)
        acc1[mi][ni] = __builtin_amdgcn_mfma_f32_16x16x32_bf16(af[mi], b1, acc1[mi][ni], 0, 0, 0);
      bf16x8 b3 = *(const bf16x8*)&B3s[kk][(wn * 64 + ni * 16 + lrow) * 32 + rq];
#pragma unroll
      for (int mi = 0; mi < 4; ++mi)
        acc3[mi][ni] = __builtin_amdgcn_mfma_f32_16x16x32_bf16(af[mi], b3, acc3[mi][ni], 0, 0, 0);
    }
    if (k + 1 < KT) {
      *(uint4*)&B1s[kk ^ 1][bws] = pack8(r1[0], r1[1]);
      *(uint4*)&B3s[kk ^ 1][bws] = pack8(r3[0], r3[1]);
    }
  }

  // epilogue: h = silu(a1)*a3 -> bf16 (padded row index)
#pragma unroll
  for (int mi = 0; mi < 4; ++mi) {
#pragma unroll
    for (int r = 0; r < 4; ++r) {
      int lr = wm * 64 + mi * 16 + quad * 4 + r;
      int p = pairs[mtile * 256 + lr];
      if (p >= 0) {
        size_t base = (size_t)(mtile * 256 + lr) * I_DIM + (size_t)ntile * 128 + wn * 64;
#pragma unroll
        for (int ni = 0; ni < 4; ++ni) {
          float v1 = acc1[mi][ni][r];
          float v3 = acc3[mi][ni][r];
          float hv = (v1 / (1.f + __expf(-v1))) * v3;
          hbuf[base + ni * 16 + lrow] = f2bf(hv);
        }
      }
    }
  }
}

// ---------------- stage2: out += h w2^T (split-K, atomic) ---------------------
// grid (8, 32, 4), block 256 = 4 waves (2x2), wave-tile 64x64. BK=32 dbuf.
__global__ __launch_bounds__(256, 4) void stage2_v6(
    const unsigned short* __restrict__ hbuf, const float* __restrict__ w2,
    const int* __restrict__ meta, const int* __restrict__ pairs,
    float* __restrict__ out)
{
  int mtile = blockIdx.y;
  if (mtile * 128 >= meta[E_NUM]) return;
  if (pairs[mtile * 128] < 0) return;      // all-padding 128-tile
  int e = 0;
  while (meta[e + 1] <= mtile * 128) ++e;
  int ntile = blockIdx.x;           // 128 cols of D
  int kbase = blockIdx.z * KCHUNK;  // 704-wide K chunk

  __shared__ alignas(16) unsigned short As[2][128 * 32];
  __shared__ alignas(16) unsigned short Bs[2][128 * 32];
  __shared__ int prow[128];

  int tid = threadIdx.x;
  for (int i = tid; i < 128; i += 256) prow[i] = pairs[mtile * 128 + i];
  __syncthreads();

  int lane = tid & 63, w = tid >> 6;
  int wm = w >> 1, wn = w & 1, lrow = lane & 15, quad = lane >> 4;
  int rq = (quad ^ SW(lrow)) * 8;

  // A staging (hbuf, bf16): wave w, issue j: rows 32w+16j+(lane/4), src pre-swizzled
  size_t axoff[2];
#pragma unroll
  for (int j = 0; j < 2; ++j) {
    int r = 32 * w + 16 * j + (lane >> 2);
    axoff[j] = (size_t)(mtile * 128 + r) * I_DIM + kbase + (((lane & 3) ^ SW(r)) * 8);
  }
  // B staging (w2, fp32): thread t, issue j: row j*64 + t/4, swizzled LDS slot
  const float* pw2[2];
  int bws[2];
#pragma unroll
  for (int j = 0; j < 2; ++j) {
    int row = j * 64 + (tid >> 2);
    pw2[j] = w2 + ((size_t)e * D_DIM + ntile * 128 + row) * I_DIM + kbase + (tid & 3) * 8;
    bws[j] = row * 32 + (((tid & 3) ^ SW(row)) * 8);
  }

  f32x4 acc[4][4];
#pragma unroll
  for (int i = 0; i < 4; ++i)
#pragma unroll
    for (int j = 0; j < 4; ++j) acc[i][j] = (f32x4){0.f, 0.f, 0.f, 0.f};

  // prologue
  float4 rb[2][2];
#pragma unroll
  for (int j = 0; j < 2; ++j) {
    rb[j][0] = *(const float4*)(pw2[j]);
    rb[j][1] = *(const float4*)(pw2[j] + 4);
    gload_lds16(hbuf + axoff[j], &As[0][(32 * w + 16 * j) * 32]);
  }
#pragma unroll
  for (int j = 0; j < 2; ++j)
    *(uint4*)&Bs[0][bws[j]] = pack8(rb[j][0], rb[j][1]);

  for (int k = 0; k < KT2; ++k) {
    __syncthreads();
    int kk = k & 1;
    if (k + 1 < KT2) {
      int kn = (k + 1) * 32;
#pragma unroll
      for (int j = 0; j < 2; ++j) {
        rb[j][0] = *(const float4*)(pw2[j] + kn);
        rb[j][1] = *(const float4*)(pw2[j] + kn + 4);
        gload_lds16(hbuf + axoff[j] + kn, &As[kk ^ 1][(32 * w + 16 * j) * 32]);
      }
    }
    bf16x8 af[4];
#pragma unroll
    for (int mi = 0; mi < 4; ++mi)
      af[mi] = *(const bf16x8*)&As[kk][(wm * 64 + mi * 16 + lrow) * 32 + rq];
#pragma unroll
    for (int ni = 0; ni < 4; ++ni) {
      bf16x8 bfr = *(const bf16x8*)&Bs[kk][(wn * 64 + ni * 16 + lrow) * 32 + rq];
#pragma unroll
      for (int mi = 0; mi < 4; ++mi)
        acc[mi][ni] = __builtin_amdgcn_mfma_f32_16x16x32_bf16(af[mi], bfr, acc[mi][ni], 0, 0, 0);
    }
    if (k + 1 < KT2) {
#pragma unroll
      for (int j = 0; j < 2; ++j)
        *(uint4*)&Bs[kk ^ 1][bws[j]] = pack8(rb[j][0], rb[j][1]);
    }
  }

  // epilogue: atomic accumulate partials
#pragma unroll
  for (int mi = 0; mi < 4; ++mi) {
#pragma unroll
    for (int r = 0; r < 4; ++r) {
      int lr = wm * 64 + mi * 16 + quad * 4 + r;
      int p = prow[lr];
      if (p >= 0) {
        float* obase = out + (size_t)p * D_DIM + (size_t)ntile * 128 + wn * 64;
#pragma unroll
        for (int ni = 0; ni < 4; ++ni)
          atomicAdd(obase + ni * 16 + lrow, acc[mi][ni][r]);
      }
    }
  }
}

extern "C" void kernel_launch(void* const* d_in, const int* in_sizes, int n_in,
                              void* d_out, int out_size, void* d_ws, size_t ws_size,
                              hipStream_t stream) {
  const float* x  = (const float*)d_in[0];
  const float* w1 = (const float*)d_in[1];
  const float* w2 = (const float*)d_in[2];
  const float* w3 = (const float*)d_in[3];
  const int* eidx = (const int*)d_in[4];
  float* out = (float*)d_out;

  int* meta  = (int*)d_ws;
  int* pairs = (int*)((char*)d_ws + 64);
  unsigned short* hbuf = (unsigned short*)((char*)d_ws + HB_OFF);
  unsigned short* xbf  = (unsigned short*)((char*)d_ws + XBF_OFF);

  sort_pairs_kernel<<<1, 256, 0, stream>>>(eidx, meta, pairs);
  convertx_kernel<<<(T_NUM * D_DIM) / 8 / 256, 256, 0, stream>>>(x, xbf);
  hipMemsetAsync(out, 0, (size_t)out_size * sizeof(float), stream);

  dim3 g1(I_DIM / 128, MT1);              // 22 x 16
  stage1_v6<<<g1, 512, 0, stream>>>(xbf, w1, w3, meta, pairs, hbuf);
  dim3 g2(D_DIM / 128, MT2, KSPLIT);      // 8 x 32 x 4
  stage2_v6<<<g2, 256, 0, stream>>>(hbuf, w2, meta, pairs, out);
}

// Round 2
// 387.046 us; speedup vs baseline: 1.0429x; 1.0429x over previous
//
#include <hip/hip_runtime.h>
#include <hip/hip_bf16.h>

#define E_NUM 8
#define I_DIM 2816
#define D_DIM 1024
#define T_NUM 1024
#define A_TOP 2
#define NPAIR (T_NUM * A_TOP)   // 2048
#define PADROWS 4096            // 256-padded worst case: 7*256 + 2048 = 3840 <= 4096
#define MT1 (PADROWS / 256)     // 16 stage1 m-tiles
#define MT2 (PADROWS / 128)     // 32 stage2 m-tiles
#define KSPLIT 4
#define KCHUNK (I_DIM / KSPLIT) // 704
#define KT2 (KCHUNK / 32)       // 22

// ws layout: [0,64) meta, [64,+PADROWS*4) pairs, hbuf @16384, xbf after
#define HB_OFF    16384ULL
#define HB_BYTES  ((unsigned long long)PADROWS * I_DIM * 2ULL)
#define XBF_OFF   (HB_OFF + HB_BYTES)

typedef __bf16 bf16x8 __attribute__((ext_vector_type(8)));
typedef float  f32x4  __attribute__((ext_vector_type(4)));

__device__ inline unsigned pk2(float a, float b) {
  __hip_bfloat162 h = __float22bfloat162_rn(make_float2(a, b));
  union { __hip_bfloat162 h; unsigned u; } c; c.h = h; return c.u;
}
__device__ inline uint4 pack8(float4 a, float4 b) {
  return make_uint4(pk2(a.x, a.y), pk2(a.z, a.w), pk2(b.x, b.y), pk2(b.z, b.w));
}
__device__ inline unsigned short f2bf(float f) {
  __hip_bfloat16 h = __float2bfloat16(f);
  union { __hip_bfloat16 h; unsigned short u; } c; c.h = h; return c.u;
}
__device__ inline void gload_lds16(const unsigned short* g, unsigned short* l) {
  __builtin_amdgcn_global_load_lds((const __attribute__((address_space(1))) void*)g,
                                   (__attribute__((address_space(3))) void*)l, 16, 0, 0);
}

// ---------------- prep: sort pairs (blk 0) + x->bf16 (blk 1..512) + zero out --
__global__ __launch_bounds__(256) void prep_kernel(
    const int* __restrict__ eidx, const float* __restrict__ x,
    int* __restrict__ meta, int* __restrict__ pairs,
    unsigned short* __restrict__ xbf, float* __restrict__ out)
{
  int bid = blockIdx.x;
  int tid = threadIdx.x;
  if (bid == 0) {
    __shared__ int cnt[E_NUM];
    __shared__ int pstart[E_NUM + 1];
    __shared__ int cur[E_NUM];
    if (tid < E_NUM) cnt[tid] = 0;
    __syncthreads();
    for (int p = tid; p < NPAIR; p += 256) atomicAdd(&cnt[eidx[p] & 7], 1);
    for (int i = tid; i < PADROWS; i += 256) pairs[i] = -1;
    __syncthreads();
    if (tid == 0) {
      int s = 0;
      for (int e = 0; e < E_NUM; ++e) {
        pstart[e] = s; cur[e] = s;
        s += ((cnt[e] + 255) / 256) * 256;   // 256-pad segments (stage1 M-tile = 256)
      }
      pstart[E_NUM] = s;
    }
    __syncthreads();
    for (int p = tid; p < NPAIR; p += 256) {
      int e = eidx[p] & 7;
      int pos = atomicAdd(&cur[e], 1);
      pairs[pos] = p;
    }
    __syncthreads();
    if (tid <= E_NUM) meta[tid] = pstart[tid];
  } else if (bid <= 512) {
    size_t i = (size_t)((bid - 1) * 256 + tid) * 8;
    const float4* p = (const float4*)(x + i);
    *(uint4*)(xbf + i) = pack8(p[0], p[1]);
  } else {
    // zero out[] : blocks 513..1024, coalesced uint4 stores
    uint4 z = make_uint4(0u, 0u, 0u, 0u);
    uint4* po = (uint4*)out + (size_t)(bid - 513) * 1024 + tid;
#pragma unroll
    for (int k = 0; k < 4; ++k) po[k * 256] = z;
  }
}

// ---------------- stage1: h = silu(X w1^T) * (X w3^T) -------------------------
// grid (44, 16), block 512 = 8 waves (4Mx2N), tile 256x64, wave-tile 64x32
// (per-wave inner loop identical to proven v5). BK=32 dbuf. LDS 49.5 KB ->
// 3 blocks/CU LDS-cap; launch_bounds(512,4) forces <=128 combined regs so
// 2 blocks (16 waves)/CU are resident. acc = 64 AGPR, vector side ~60.
__global__ __launch_bounds__(512, 4) void stage1_v7(
    const unsigned short* __restrict__ xbf, const float* __restrict__ w1,
    const float* __restrict__ w3, const int* __restrict__ meta,
    const int* __restrict__ pairs, unsigned short* __restrict__ hbuf)
{
  int mtile = blockIdx.y;
  if (mtile * 256 >= meta[E_NUM]) return;
  if (pairs[mtile * 256] < 0) return;      // all-padding 256-tile
  int e = 0;
  while (meta[e + 1] <= mtile * 256) ++e;
  int ntile = blockIdx.x;   // 64 cols of I

  __shared__ alignas(16) unsigned short As[2][256 * 32];   // 32 KB
  __shared__ alignas(16) unsigned short B1s[2][64 * 32];   // 8 KB
  __shared__ alignas(16) unsigned short B3s[2][64 * 32];   // 8 KB
  __shared__ int prow[256];

  int tid = threadIdx.x;
  for (int i = tid; i < 256; i += 512) prow[i] = pairs[mtile * 256 + i];
  __syncthreads();

  int lane = tid & 63, w = tid >> 6;       // 8 waves
  int wm = w >> 1, wn = w & 1;             // 4M x 2N
  int lrow = lane & 15, quad = lane >> 4;

  // A staging: wave w stages rows 32w..32w+31 (2 issues x 16 rows)
  int axoff[2];
#pragma unroll
  for (int j = 0; j < 2; ++j) {
    int r = 32 * w + 16 * j + (lane >> 2);
    int p = prow[r];
    int tok = (p >= 0) ? (p >> 1) : 0;
    axoff[j] = tok * D_DIM + (lane & 3) * 8;
  }
  // B staging: threads [0,256) stage w1, [256,512) stage w3 (wave-uniform split)
  int mat = tid >> 8;                      // 0: w1, 1: w3
  int bt = tid & 255;
  int brow = bt >> 2, bchunk = bt & 3;     // 64 rows x 4 chunks
  const float* pw = (mat ? w3 : w1) +
      ((size_t)e * I_DIM + ntile * 64 + brow) * D_DIM + bchunk * 8;
  int bws = brow * 32 + bchunk * 8;
  unsigned short* bls[2];
  bls[0] = mat ? B3s[0] : B1s[0];
  bls[1] = mat ? B3s[1] : B1s[1];

  f32x4 acc1[4][2], acc3[4][2];
#pragma unroll
  for (int i = 0; i < 4; ++i)
#pragma unroll
    for (int j = 0; j < 2; ++j) {
      acc1[i][j] = (f32x4){0.f, 0.f, 0.f, 0.f};
      acc3[i][j] = (f32x4){0.f, 0.f, 0.f, 0.f};
    }

  // prologue: K-tile 0
  float4 rb[2];
  rb[0] = *(const float4*)(pw);
  rb[1] = *(const float4*)(pw + 4);
  gload_lds16(xbf + axoff[0], &As[0][(32 * w) * 32]);
  gload_lds16(xbf + axoff[1], &As[0][(32 * w + 16) * 32]);
  *(uint4*)&bls[0][bws] = pack8(rb[0], rb[1]);

  const int KT = D_DIM / 32;   // 32
  for (int k = 0; k < KT; ++k) {
    __syncthreads();
    int kk = k & 1;
    if (k + 1 < KT) {
      int kn = (k + 1) * 32;
      rb[0] = *(const float4*)(pw + kn);
      rb[1] = *(const float4*)(pw + kn + 4);
      gload_lds16(xbf + axoff[0] + kn, &As[kk ^ 1][(32 * w) * 32]);
      gload_lds16(xbf + axoff[1] + kn, &As[kk ^ 1][(32 * w + 16) * 32]);
    }
    bf16x8 af[4];
#pragma unroll
    for (int mi = 0; mi < 4; ++mi)
      af[mi] = *(const bf16x8*)&As[kk][(wm * 64 + mi * 16 + lrow) * 32 + quad * 8];
#pragma unroll
    for (int ni = 0; ni < 2; ++ni) {
      bf16x8 b1 = *(const bf16x8*)&B1s[kk][(wn * 32 + ni * 16 + lrow) * 32 + quad * 8];
#pragma unroll
      for (int mi = 0; mi < 4; ++mi)
        acc1[mi][ni] = __builtin_amdgcn_mfma_f32_16x16x32_bf16(af[mi], b1, acc1[mi][ni], 0, 0, 0);
      bf16x8 b3 = *(const bf16x8*)&B3s[kk][(wn * 32 + ni * 16 + lrow) * 32 + quad * 8];
#pragma unroll
      for (int mi = 0; mi < 4; ++mi)
        acc3[mi][ni] = __builtin_amdgcn_mfma_f32_16x16x32_bf16(af[mi], b3, acc3[mi][ni], 0, 0, 0);
    }
    if (k + 1 < KT) {
      *(uint4*)&bls[kk ^ 1][bws] = pack8(rb[0], rb[1]);
    }
  }

  // epilogue: h = silu(a1)*a3 -> bf16 (padded row index)
#pragma unroll
  for (int mi = 0; mi < 4; ++mi) {
#pragma unroll
    for (int r = 0; r < 4; ++r) {
      int lr = wm * 64 + mi * 16 + quad * 4 + r;
      int p = prow[lr];
      if (p >= 0) {
        size_t base = (size_t)(mtile * 256 + lr) * I_DIM + (size_t)ntile * 64 + wn * 32;
#pragma unroll
        for (int ni = 0; ni < 2; ++ni) {
          float v1 = acc1[mi][ni][r];
          float v3 = acc3[mi][ni][r];
          float hv = (v1 / (1.f + __expf(-v1))) * v3;
          hbuf[base + ni * 16 + lrow] = f2bf(hv);
        }
      }
    }
  }
}

// ---------------- stage2: out += h w2^T (split-K, atomic) ---------------------
// grid (8, 32, 4), block 256 = 4 waves (2x2), wave-tile 64x64. BK=32 dbuf.
__global__ __launch_bounds__(256, 4) void stage2_v7(
    const unsigned short* __restrict__ hbuf, const float* __restrict__ w2,
    const int* __restrict__ meta, const int* __restrict__ pairs,
    float* __restrict__ out)
{
  int mtile = blockIdx.y;
  if (mtile * 128 >= meta[E_NUM]) return;
  if (pairs[mtile * 128] < 0) return;      // all-padding 128-tile
  int e = 0;
  while (meta[e + 1] <= mtile * 128) ++e;
  int ntile = blockIdx.x;           // 128 cols of D
  int kbase = blockIdx.z * KCHUNK;  // 704-wide K chunk

  __shared__ alignas(16) unsigned short As[2][128 * 32];
  __shared__ alignas(16) unsigned short Bs[2][128 * 32];
  __shared__ int prow[128];

  int tid = threadIdx.x;
  for (int i = tid; i < 128; i += 256) prow[i] = pairs[mtile * 128 + i];
  __syncthreads();

  int lane = tid & 63, w = tid >> 6;
  int wm = w >> 1, wn = w & 1, lrow = lane & 15, quad = lane >> 4;

  // A staging (hbuf, bf16): wave w, issue j: rows 32w+16j+(lane/4)
  size_t axoff[2];
#pragma unroll
  for (int j = 0; j < 2; ++j) {
    int r = 32 * w + 16 * j + (lane >> 2);
    axoff[j] = (size_t)(mtile * 128 + r) * I_DIM + kbase + (lane & 3) * 8;
  }
  // B staging (w2, fp32): thread t, issue j: row j*64 + t/4, col (t%4)*8
  const float* pw2[2];
  int bws[2];
#pragma unroll
  for (int j = 0; j < 2; ++j) {
    int row = j * 64 + (tid >> 2);
    pw2[j] = w2 + ((size_t)e * D_DIM + ntile * 128 + row) * I_DIM + kbase + (tid & 3) * 8;
    bws[j] = row * 32 + (tid & 3) * 8;
  }

  f32x4 acc[4][4];
#pragma unroll
  for (int i = 0; i < 4; ++i)
#pragma unroll
    for (int j = 0; j < 4; ++j) acc[i][j] = (f32x4){0.f, 0.f, 0.f, 0.f};

  // prologue
  float4 rb[2][2];
#pragma unroll
  for (int j = 0; j < 2; ++j) {
    rb[j][0] = *(const float4*)(pw2[j]);
    rb[j][1] = *(const float4*)(pw2[j] + 4);
    gload_lds16(hbuf + axoff[j], &As[0][(32 * w + 16 * j) * 32]);
  }
#pragma unroll
  for (int j = 0; j < 2; ++j)
    *(uint4*)&Bs[0][bws[j]] = pack8(rb[j][0], rb[j][1]);

  for (int k = 0; k < KT2; ++k) {
    __syncthreads();
    int kk = k & 1;
    if (k + 1 < KT2) {
      int kn = (k + 1) * 32;
#pragma unroll
      for (int j = 0; j < 2; ++j) {
        rb[j][0] = *(const float4*)(pw2[j] + kn);
        rb[j][1] = *(const float4*)(pw2[j] + kn + 4);
        gload_lds16(hbuf + axoff[j] + kn, &As[kk ^ 1][(32 * w + 16 * j) * 32]);
      }
    }
    bf16x8 af[4];
#pragma unroll
    for (int mi = 0; mi < 4; ++mi)
      af[mi] = *(const bf16x8*)&As[kk][(wm * 64 + mi * 16 + lrow) * 32 + quad * 8];
#pragma unroll
    for (int ni = 0; ni < 4; ++ni) {
      bf16x8 bfr = *(const bf16x8*)&Bs[kk][(wn * 64 + ni * 16 + lrow) * 32 + quad * 8];
#pragma unroll
      for (int mi = 0; mi < 4; ++mi)
        acc[mi][ni] = __builtin_amdgcn_mfma_f32_16x16x32_bf16(af[mi], bfr, acc[mi][ni], 0, 0, 0);
    }
    if (k + 1 < KT2) {
#pragma unroll
      for (int j = 0; j < 2; ++j)
        *(uint4*)&Bs[kk ^ 1][bws[j]] = pack8(rb[j][0], rb[j][1]);
    }
  }

  // epilogue: atomic accumulate partials
#pragma unroll
  for (int mi = 0; mi < 4; ++mi) {
#pragma unroll
    for (int r = 0; r < 4; ++r) {
      int lr = wm * 64 + mi * 16 + quad * 4 + r;
      int p = prow[lr];
      if (p >= 0) {
        float* obase = out + (size_t)p * D_DIM + (size_t)ntile * 128 + wn * 64;
#pragma unroll
        for (int ni = 0; ni < 4; ++ni)
          atomicAdd(obase + ni * 16 + lrow, acc[mi][ni][r]);
      }
    }
  }
}

extern "C" void kernel_launch(void* const* d_in, const int* in_sizes, int n_in,
                              void* d_out, int out_size, void* d_ws, size_t ws_size,
                              hipStream_t stream) {
  const float* x  = (const float*)d_in[0];
  const float* w1 = (const float*)d_in[1];
  const float* w2 = (const float*)d_in[2];
  const float* w3 = (const float*)d_in[3];
  const int* eidx = (const int*)d_in[4];
  float* out = (float*)d_out;

  int* meta  = (int*)d_ws;
  int* pairs = (int*)((char*)d_ws + 64);
  unsigned short* hbuf = (unsigned short*)((char*)d_ws + HB_OFF);
  unsigned short* xbf  = (unsigned short*)((char*)d_ws + XBF_OFF);

  // prep: block 0 sorts, blocks 1..512 convert x, blocks 513..1024 zero out
  prep_kernel<<<1025, 256, 0, stream>>>(eidx, x, meta, pairs, xbf, out);

  dim3 g1(I_DIM / 64, MT1);               // 44 x 16
  stage1_v7<<<g1, 512, 0, stream>>>(xbf, w1, w3, meta, pairs, hbuf);
  dim3 g2(D_DIM / 128, MT2, KSPLIT);      // 8 x 32 x 4
  stage2_v7<<<g2, 256, 0, stream>>>(hbuf, w2, meta, pairs, out);
}